// Round 3
// baseline (168.446 us; speedup 1.0000x reference)
//
#include <hip/hip_runtime.h>
#include <hip/hip_bf16.h>

// Binarized conv block (XNOR-net style):
//   a  = sign(x + bias1)          in {+1,-1},  sign(0)=+1
//   qk = sign(kernel)             in {+1,-1}
//   y  = conv2d(a, qk, SAME, s=1) NHWC/HWIO, B=32 H=W=56 Cin=Cout=256
//   out = relu((y - mean)*rsqrt(var+eps) + beta + bias2), eps=1e-3
//
// +-1 dot over Cin=256  ==  256 - 2*popcount(xor of 256-bit packed operands).
// Zero-padding in the conv is handled by packing a into a zero-padded
// [32][58][58][4]-u64 array: pad words are all-zero bits (decode as a=-1),
// and each thread subtracts the exact correction pcw[tap] = 256-2*popcount(w)
// for every pad tap, making the 9-tap inner loop branch-free.
// Corners: a tap can be pad via BOTH row and column — subtract overlap once.
//
// NOTE: pad zeroing is done by a kernel (zero_pa_kernel), NOT hipMemsetAsync —
// the memset did not take effect under graph replay (post-timing divergence
// with 0xAA-poison signature in the pad ring).

#define B   32
#define HW  56
#define HP  58          // padded spatial dim
#define CIN 256
#define COUT 256
#define CHUNKS 4        // 256 bits = 4 x u64

typedef unsigned long long u64;

// ---------------- zero the padded activation array ----------------
__global__ __launch_bounds__(256) void zero_pa_kernel(u64* __restrict__ pa)
{
    const size_t i = (size_t)blockIdx.x * 256 + threadIdx.x;
    pa[i] = 0ull;        // grid sized to cover exactly B*HP*HP*CHUNKS
}

// ---------------- pack activations: x + bias1 -> sign bits ----------------
// one wave packs one pixel (4 ballots of 64 channels each)
__global__ __launch_bounds__(256) void pack_a_kernel(
    const float* __restrict__ x, const float* __restrict__ b1,
    u64* __restrict__ pa)
{
    const int wave = threadIdx.x >> 6;
    const int lane = threadIdx.x & 63;
    const int pixel = blockIdx.x * 4 + wave;          // grid covers exactly B*HW*HW
    const int n = pixel / (HW * HW);
    const int rem = pixel % (HW * HW);
    const int h = rem / HW, w = rem % HW;

    const float* xp = x + (size_t)pixel * CIN;
    const size_t po = (((size_t)n * HP + (h + 1)) * HP + (w + 1)) * CHUNKS;
#pragma unroll
    for (int c = 0; c < CHUNKS; ++c) {
        const int ch = c * 64 + lane;
        const u64 m = __ballot(xp[ch] + b1[ch] >= 0.0f);
        if (lane == 0) pa[po + c] = m;
    }
}

// ---------------- pack weights: sign(kernel) -> bits ----------------
// layout pk[tap][chunk][cout] so conv weight loads are coalesced over cout.
// one wave handles one (tap, cout) pair.
__global__ __launch_bounds__(256) void pack_k_kernel(
    const float* __restrict__ k, u64* __restrict__ pk)
{
    const int wave = threadIdx.x >> 6;
    const int lane = threadIdx.x & 63;
    const int idx = blockIdx.x * 4 + wave;            // 0 .. 9*COUT-1
    const int tap = idx >> 8;
    const int cout = idx & 255;
#pragma unroll
    for (int c = 0; c < CHUNKS; ++c) {
        const int cin = c * 64 + lane;
        const float v = k[((size_t)tap * CIN + cin) * COUT + cout];
        const u64 m = __ballot(v >= 0.0f);
        if (lane == 0) pk[((size_t)tap * CHUNKS + c) * COUT + cout] = m;
    }
}

// ---------------- binarized conv + BN + bias + relu ----------------
// block = 256 threads (4 waves); thread t <-> cout t; block <-> one (n,h) row.
// a-window addresses are wave-uniform -> scalar loads (SGPR), weights live in
// VGPRs, xor pairs SGPR a-word with VGPR weight. Stores coalesced over cout.
__global__ __launch_bounds__(256) void conv_bin_kernel(
    const u64* __restrict__ pa, const u64* __restrict__ pk,
    const float* __restrict__ beta, const float* __restrict__ mean,
    const float* __restrict__ var, const float* __restrict__ bias2,
    float* __restrict__ out)
{
    const int t  = threadIdx.x;          // cout
    const int bh = blockIdx.x;           // n*HW + h
    const int n  = bh / HW, h = bh % HW;

    // per-cout weights (36 u64 in VGPRs) + pad-tap corrections
    u64 w[9][CHUNKS];
    int pcw[9];                          // spurious dot a pad tap contributes
#pragma unroll
    for (int tap = 0; tap < 9; ++tap) {
        int pc = 0;
#pragma unroll
        for (int c = 0; c < CHUNKS; ++c) {
            w[tap][c] = pk[((size_t)tap * CHUNKS + c) * COUT + t];
            pc += __popcll(w[tap][c]);
        }
        pcw[tap] = CIN - 2 * pc;
    }
    const bool top = (h == 0), bot = (h == HW - 1);
    const int cT = top ? pcw[0] + pcw[1] + pcw[2] : 0;
    const int cB = bot ? pcw[6] + pcw[7] + pcw[8] : 0;
    // left/right column corrections, minus the row-overlap tap already
    // counted in cT/cB (corner pixels: tap pad by both row AND column)
    const int oL = (top ? pcw[0] : 0) + (bot ? pcw[6] : 0);
    const int oR = (top ? pcw[2] : 0) + (bot ? pcw[8] : 0);
    const int cL = pcw[0] + pcw[3] + pcw[6] - oL;
    const int cR = pcw[2] + pcw[5] + pcw[8] - oR;
    const int cbase = cT + cB;

    // folded BN + bias2:  out = relu(y*s + tt)
    const float s  = 1.0f / sqrtf(var[t] + 1e-3f);
    const float tt = beta[t] - mean[t] * s + bias2[t];

    // padded row pointers: output row h reads padded rows h, h+1, h+2
    const u64* r0 = pa + (((size_t)n * HP + h) * HP) * CHUNKS;
    const u64* r1 = r0 + (size_t)HP * CHUNKS;
    const u64* r2 = r1 + (size_t)HP * CHUNKS;
    float* op = out + (size_t)bh * HW * COUT + t;

    for (int wx = 0; wx < HW; ++wx) {
        const u64* a0 = r0 + (size_t)wx * CHUNKS;    // padded col wx+kx
        const u64* a1 = r1 + (size_t)wx * CHUNKS;
        const u64* a2 = r2 + (size_t)wx * CHUNKS;
        int acc0 = 0, acc1 = 0, acc2 = 0;
#pragma unroll
        for (int kx = 0; kx < 3; ++kx) {
#pragma unroll
            for (int c = 0; c < CHUNKS; ++c) {
                acc0 += __popcll(a0[kx * CHUNKS + c] ^ w[0 * 3 + kx][c]);
                acc1 += __popcll(a1[kx * CHUNKS + c] ^ w[1 * 3 + kx][c]);
                acc2 += __popcll(a2[kx * CHUNKS + c] ^ w[2 * 3 + kx][c]);
            }
        }
        const int corr = cbase + (wx == 0 ? cL : 0) + (wx == HW - 1 ? cR : 0);
        const float y = (float)(9 * CIN - 2 * (acc0 + acc1 + acc2) - corr);
        op[(size_t)wx * COUT] = fmaxf(fmaf(y, s, tt), 0.0f);
    }
}

extern "C" void kernel_launch(void* const* d_in, const int* in_sizes, int n_in,
                              void* d_out, int out_size, void* d_ws, size_t ws_size,
                              hipStream_t stream)
{
    const float* x      = (const float*)d_in[0];
    const float* bias1  = (const float*)d_in[1];
    const float* kernel = (const float*)d_in[2];
    const float* bn_beta = (const float*)d_in[3];
    const float* bn_mean = (const float*)d_in[4];
    const float* bn_var  = (const float*)d_in[5];
    const float* bias2   = (const float*)d_in[6];
    float* out = (float*)d_out;

    u64* pa = (u64*)d_ws;                                  // padded packed activations
    const size_t pa_elems = (size_t)B * HP * HP * CHUNKS;  // 430,592 u64 = 3.44 MB
    u64* pk = pa + pa_elems;                               // packed weights, 9216 u64

    // zero the padded activation array with a kernel (graph-capture safe)
    zero_pa_kernel<<<dim3((int)(pa_elems / 256)), dim3(256), 0, stream>>>(pa);

    const int npix = B * HW * HW;                          // 100352
    pack_a_kernel<<<dim3(npix / 4), dim3(256), 0, stream>>>(x, bias1, pa);
    pack_k_kernel<<<dim3(9 * COUT / 4), dim3(256), 0, stream>>>(kernel, pk);
    conv_bin_kernel<<<dim3(B * HW), dim3(256), 0, stream>>>(
        pa, pk, bn_beta, bn_mean, bn_var, bias2, out);
}